// Round 7
// baseline (1530.930 us; speedup 1.0000x reference)
//
#include <hip/hip_runtime.h>
#include <cfloat>
#include <cstdint>
#include <cstddef>

#define NTOK 8192
#define NE   8192
#define DIM  512
#define OUT0 4194304   // floats in x_q_st region

// ---------------- fp64 exp, branchless, |x| <= ~482*ln2 ----------------
__device__ __forceinline__ double fexp_d(double x){
  const double L2E = 1.4426950408889634074;
  const double LN2 = 0.69314718055994530942;
  double kd = rint(x * L2E);
  double r  = fma(-kd, LN2, x);                 // |r| <= 0.3466
  double p = 2.4801587301587301566e-05;         // 1/8!
  p = fma(p, r, 1.9841269841269841253e-04);     // 1/7!
  p = fma(p, r, 1.3888888888888889419e-03);     // 1/6!
  p = fma(p, r, 8.3333333333333332177e-03);     // 1/5!
  p = fma(p, r, 4.1666666666666664354e-02);     // 1/4!
  p = fma(p, r, 1.6666666666666665741e-01);     // 1/3!
  p = fma(p, r, 5.0e-01);
  p = fma(p, r, 1.0);
  p = fma(p, r, 1.0);
  long long eb = ((long long)(1023 + (int)kd)) << 52;
  return p * __longlong_as_double(eb);
}

__device__ __forceinline__ unsigned int f2ord(float f){
  unsigned int u = __float_as_uint(f);
  return (u & 0x80000000u) ? ~u : (u | 0x80000000u);
}
__device__ __forceinline__ float ord2f(unsigned int v){
  unsigned int u = (v & 0x80000000u) ? (v ^ 0x80000000u) : ~v;
  return __uint_as_float(u);
}

// ---------------- numpy pairwise sum of squares (exact order) ----------------
__device__ float pw128_sq(const float* __restrict__ p){
  float r[8];
#pragma unroll
  for (int j = 0; j < 8; ++j) r[j] = __fmul_rn(p[j], p[j]);
#pragma unroll
  for (int i = 8; i < 128; i += 8)
#pragma unroll
    for (int j = 0; j < 8; ++j) r[j] = __fadd_rn(r[j], __fmul_rn(p[i+j], p[i+j]));
  float s01 = __fadd_rn(r[0], r[1]), s23 = __fadd_rn(r[2], r[3]);
  float s45 = __fadd_rn(r[4], r[5]), s67 = __fadd_rn(r[6], r[7]);
  return __fadd_rn(__fadd_rn(s01, s23), __fadd_rn(s45, s67));
}
__device__ float pw512_sq(const float* __restrict__ p){
  float s0 = __fadd_rn(pw128_sq(p),       pw128_sq(p + 128));
  float s1 = __fadd_rn(pw128_sq(p + 256), pw128_sq(p + 384));
  return __fadd_rn(s0, s1);
}

// blocks 0..31 -> X norms, 32..63 -> E norms
__global__ __launch_bounds__(256) void normsK(const float* __restrict__ X, const float* __restrict__ E,
    float* __restrict__ avec, float* __restrict__ hvec){
  int blk = blockIdx.x;
  int i = (blk & 31) * 256 + threadIdx.x;
  if (blk < 32) avec[i] = pw512_sq(X + (size_t)i * DIM);
  else          hvec[i] = pw512_sq(E + (size_t)i * DIM);
}

__global__ void initK(unsigned int* sc32){
  if (threadIdx.x == 0){ sc32[0] = 0u; sc32[1] = 0xFFFFFFFFu; }
}

__global__ void finalizeK(const unsigned int* sc32, float* scf){
  if (threadIdx.x == 0){
    float mx = ord2f(sc32[0]);
    float mn = ord2f(sc32[1]);
    float middle = __fmul_rn(__fadd_rn(mx, mn), 0.5f);
    float amp    = __fadd_rn(__fsub_rn(mx, middle), 1e-5f);
    scf[0] = middle; scf[1] = amp;
  }
}

__global__ void diagK(float* __restrict__ out, int n, float tag){
  int i = blockIdx.x * blockDim.x + threadIdx.x;
  int stride = gridDim.x * blockDim.x;
  for (; i < n; i += stride) out[i] = (i == OUT0) ? tag : 0.f;
}

// ---------------- fp32 GEMM 128x256x16, 8x16/thread, k-ascending FMA ----------------
// 0.75 B/FMA LDS demand (vs 1.0 at 8x8); 256-cy FMA bursts hide ds_read latency.
// Banks: As 4-addr x16-lane broadcast (free); Bs/writes 2-way (free, m136).
// launch_bounds(256,2): VGPR cap 256, actual ~190 — no spill (cap 85 spilled; cap 128 ok).
#define GBM 128
#define GBN 256
#define GBK 16
#define LDA 132
#define LDB 260
__global__ __launch_bounds__(256, 2) void gemm128(const float* __restrict__ X, const float* __restrict__ E,
    const float* __restrict__ avec, const float* __restrict__ hvec,
    float* __restrict__ dmat, unsigned int* __restrict__ sc32){
  __shared__ float As[GBK][LDA];
  __shared__ float Bs[GBK][LDB];
  __shared__ float red[256];
  int tid = threadIdx.x;
  int tx = tid & 15, ty = tid >> 4;
  int bm = blockIdx.y * GBM, bn = blockIdx.x * GBN;

  float acc[2][4][4][4];
#pragma unroll
  for (int ih = 0; ih < 2; ++ih)
#pragma unroll
    for (int i = 0; i < 4; ++i)
#pragma unroll
      for (int jh = 0; jh < 4; ++jh)
#pragma unroll
        for (int j = 0; j < 4; ++j) acc[ih][i][jh][j] = 0.f;

  for (int kt = 0; kt < DIM; kt += GBK){
    // stage A: 512 float4 (s=0..1), B: 1024 float4 (s=2..5)
#pragma unroll
    for (int s = 0; s < 2; ++s){
      int flat = tid + s * 256;            // 0..511
      int m  = flat >> 2;                  // 0..127
      int k4 = (flat & 3) * 4;
      float4 va = *(const float4*)(X + (size_t)(bm + m) * DIM + kt + k4);
      As[k4+0][m] = va.x; As[k4+1][m] = va.y; As[k4+2][m] = va.z; As[k4+3][m] = va.w;
    }
#pragma unroll
    for (int s = 0; s < 4; ++s){
      int flat = tid + s * 256;            // 0..1023
      int m  = flat >> 2;                  // 0..255
      int k4 = (flat & 3) * 4;
      float4 vb = *(const float4*)(E + (size_t)(bn + m) * DIM + kt + k4);
      Bs[k4+0][m] = vb.x; Bs[k4+1][m] = vb.y; Bs[k4+2][m] = vb.z; Bs[k4+3][m] = vb.w;
    }
    __syncthreads();
#pragma unroll
    for (int kk = 0; kk < GBK; ++kk){
      float a[2][4], b[4][4];
      *(float4*)a[0] = *(const float4*)&As[kk][ty * 4];
      *(float4*)a[1] = *(const float4*)&As[kk][64 + ty * 4];
#pragma unroll
      for (int jh = 0; jh < 4; ++jh)
        *(float4*)b[jh] = *(const float4*)&Bs[kk][jh * 64 + tx * 4];
#pragma unroll
      for (int ih = 0; ih < 2; ++ih)
#pragma unroll
        for (int i = 0; i < 4; ++i)
#pragma unroll
          for (int jh = 0; jh < 4; ++jh)
#pragma unroll
            for (int j = 0; j < 4; ++j)
              acc[ih][i][jh][j] = fmaf(a[ih][i], b[jh][j], acc[ih][i][jh][j]);
    }
    __syncthreads();
  }

  float lmax = -FLT_MAX, lmin = FLT_MAX;
#pragma unroll
  for (int ih = 0; ih < 2; ++ih){
#pragma unroll
    for (int i = 0; i < 4; ++i){
      int gr = bm + ih * 64 + ty * 4 + i;
      float a = avec[gr];
#pragma unroll
      for (int jh = 0; jh < 4; ++jh){
        float dv[4];
#pragma unroll
        for (int j = 0; j < 4; ++j){
          int gc = bn + jh * 64 + tx * 4 + j;
          float t = __fadd_rn(a, hvec[gc]);                  // fl(a_b + h_k)
          float d = __fsub_rn(t, 2.0f * acc[ih][i][jh][j]);  // fl(t - 2c)
          dv[j] = d;
          lmax = fmaxf(lmax, d); lmin = fminf(lmin, d);
        }
        *(float4*)(dmat + (size_t)gr * NE + bn + jh * 64 + tx * 4) = *(float4*)&dv[0];
      }
    }
  }
  red[tid] = lmax; __syncthreads();
  for (int s = 128; s > 0; s >>= 1){ if (tid < s) red[tid] = fmaxf(red[tid], red[tid+s]); __syncthreads(); }
  float bmax = red[0];
  __syncthreads();
  red[tid] = lmin; __syncthreads();
  for (int s = 128; s > 0; s >>= 1){ if (tid < s) red[tid] = fminf(red[tid], red[tid+s]); __syncthreads(); }
  if (tid == 0){
    atomicMax(&sc32[0], f2ord(bmax));
    atomicMin(&sc32[1], f2ord(red[0]));
  }
}

// ---------------- Sinkhorn sweeps ----------------
#define EXPD(x) fexp_d((double)__fdiv_rn(__fsub_rn((x), middle), amp) * NIE)

// row step: r_k = sum_b exp(L[b,k]) * w_b ; 4 independent per-k fp64 chains per thread.
// grid (8, 128): 1024 blocks; 64-row chunks (fp64 reassoc only, safe)
__global__ __launch_bounds__(256) void rowPassK(const float* __restrict__ dmat, const double* __restrict__ wvec,
    const float* __restrict__ scf, double* __restrict__ partials){
  int tid = threadIdx.x;
  int k0 = (blockIdx.x * 256 + tid) * 4;
  int b0 = blockIdx.y * 64;
  float middle = scf[0], amp = scf[1];
  const double NIE = -(1.0 / 0.003);
  const float* p = dmat + (size_t)b0 * NE + k0;
  double a0 = 0.0, a1 = 0.0, a2 = 0.0, a3 = 0.0;
  if (wvec){
    for (int bb = 0; bb < 64; bb += 2){
      float4 v0 = *(const float4*)(p + (size_t)(bb+0) * NE);
      float4 v1 = *(const float4*)(p + (size_t)(bb+1) * NE);
      double w0 = wvec[b0+bb+0], w1 = wvec[b0+bb+1];
      a0 = fma(EXPD(v0.x), w0, a0); a1 = fma(EXPD(v0.y), w0, a1);
      a2 = fma(EXPD(v0.z), w0, a2); a3 = fma(EXPD(v0.w), w0, a3);
      a0 = fma(EXPD(v1.x), w1, a0); a1 = fma(EXPD(v1.y), w1, a1);
      a2 = fma(EXPD(v1.z), w1, a2); a3 = fma(EXPD(v1.w), w1, a3);
    }
  } else {
    for (int bb = 0; bb < 64; bb += 2){
      float4 v0 = *(const float4*)(p + (size_t)(bb+0) * NE);
      float4 v1 = *(const float4*)(p + (size_t)(bb+1) * NE);
      a0 += EXPD(v0.x); a1 += EXPD(v0.y); a2 += EXPD(v0.z); a3 += EXPD(v0.w);
      a0 += EXPD(v1.x); a1 += EXPD(v1.y); a2 += EXPD(v1.z); a3 += EXPD(v1.w);
    }
  }
  double* q = partials + (size_t)blockIdx.y * NE + k0;
  q[0] = a0; q[1] = a1; q[2] = a2; q[3] = a3;
}

__global__ void reduceAK(const double* __restrict__ partials, double* __restrict__ ak){
  int k = blockIdx.x * 256 + threadIdx.x;
  double s = 0.0;
  for (int c = 0; c < 128; ++c) s += partials[(size_t)c * NE + k];
  ak[k] = 1.0 / (8192.0 * s);
}

// col step: 4 independent fp64 chains per thread (k = tid + 256*(m+4i)), combined at end
__global__ __launch_bounds__(256) void colPassK(const float* __restrict__ dmat, const double* __restrict__ ak,
    const float* __restrict__ scf, double* __restrict__ bvec){
  __shared__ double sd[256];
  int b = blockIdx.x, tid = threadIdx.x;
  float middle = scf[0], amp = scf[1];
  const double NIE = -(1.0 / 0.003);
  const float* row = dmat + (size_t)b * NE;
  double c0 = 0.0, c1 = 0.0, c2 = 0.0, c3 = 0.0;
  for (int kb = 0; kb < 32; kb += 4){
    int k0 = tid + (kb+0) * 256, k1 = tid + (kb+1) * 256, k2 = tid + (kb+2) * 256, k3 = tid + (kb+3) * 256;
    float r0 = row[k0], r1 = row[k1], r2 = row[k2], r3 = row[k3];
    double q0 = ak[k0], q1 = ak[k1], q2 = ak[k2], q3 = ak[k3];
    c0 = fma(EXPD(r0), q0, c0);
    c1 = fma(EXPD(r1), q1, c1);
    c2 = fma(EXPD(r2), q2, c2);
    c3 = fma(EXPD(r3), q3, c3);
  }
  sd[tid] = (c0 + c1) + (c2 + c3); __syncthreads();
  for (int s = 128; s > 0; s >>= 1){ if (tid < s) sd[tid] += sd[tid+s]; __syncthreads(); }
  if (tid == 0) bvec[b] = 1.0 / (8192.0 * sd[0]);
}

__global__ void lnaK(const double* __restrict__ ak, double* __restrict__ lna){
  int k = blockIdx.x * 256 + threadIdx.x;
  lna[k] = log(ak[k]);
}

// argmax_k [ ln a_k + L[b,k] ] fused with loss partial for the token
__global__ __launch_bounds__(256) void argmaxLossK(const float* __restrict__ dmat, const double* __restrict__ lna,
    const float* __restrict__ scf, const float* __restrict__ X, const float* __restrict__ E,
    float* __restrict__ idxF, double* __restrict__ lparts){
  __shared__ double sv[256];
  __shared__ int    si[256];
  __shared__ int    sidx;
  int b = blockIdx.x, tid = threadIdx.x;
  float middle = scf[0], amp = scf[1];
  const double NIE = -(1.0 / 0.003);
  const float* row = dmat + (size_t)b * NE;
  double best = -1.0e300; int bk = NE;
#pragma unroll 2
  for (int c = 0; c < 8; ++c){
    int k = c * 1024 + tid * 4;
    float4 v = *(const float4*)(row + k);
    double l0 = lna[k], l1 = lna[k+1], l2 = lna[k+2], l3 = lna[k+3];
    double t0 = fma((double)__fdiv_rn(__fsub_rn(v.x, middle), amp), NIE, l0);
    double t1 = fma((double)__fdiv_rn(__fsub_rn(v.y, middle), amp), NIE, l1);
    double t2 = fma((double)__fdiv_rn(__fsub_rn(v.z, middle), amp), NIE, l2);
    double t3 = fma((double)__fdiv_rn(__fsub_rn(v.w, middle), amp), NIE, l3);
    if (t0 > best){ best = t0; bk = k; }
    if (t1 > best){ best = t1; bk = k+1; }
    if (t2 > best){ best = t2; bk = k+2; }
    if (t3 > best){ best = t3; bk = k+3; }
  }
  sv[tid] = best; si[tid] = bk; __syncthreads();
  for (int s = 128; s > 0; s >>= 1){
    if (tid < s){
      double o = sv[tid+s]; int ok = si[tid+s];
      if (o > sv[tid] || (o == sv[tid] && ok < si[tid])){ sv[tid] = o; si[tid] = ok; }
    }
    __syncthreads();
  }
  if (tid == 0){ idxF[b] = (float)si[0]; sidx = si[0]; }
  __syncthreads();

  // fused loss partial
  int id = sidx;
  const float* xr = X + (size_t)b * DIM;
  const float* er = E + (size_t)id * DIM;
  double ls = 0.0;
#pragma unroll
  for (int c = 0; c < 2; ++c){
    int dpos = tid + c * 256;
    float diff = __fsub_rn(er[dpos], xr[dpos]);
    ls = fma((double)diff, (double)diff, ls);
  }
  sv[tid] = ls; __syncthreads();
  for (int s = 128; s > 0; s >>= 1){ if (tid < s) sv[tid] += sv[tid+s]; __syncthreads(); }
  if (tid == 0) lparts[b] = sv[0];
}

__global__ __launch_bounds__(256) void lossFinK(const double* __restrict__ lparts, float* __restrict__ lossOut){
  __shared__ double sd[256];
  int tid = threadIdx.x;
  double s = 0.0;
  for (int b = tid; b < NTOK; b += 256) s += lparts[b];
  sd[tid] = s; __syncthreads();
  for (int st = 128; st > 0; st >>= 1){ if (tid < st) sd[tid] += sd[tid+st]; __syncthreads(); }
  if (tid == 0){
    double v = sd[0] / (double)((size_t)NTOK * DIM);
    float vf = (float)v;
    lossOut[0] = __fadd_rn(vf, __fmul_rn(0.25f, vf));
  }
}

__global__ __launch_bounds__(256) void out0K(const float* __restrict__ X, const float* __restrict__ E,
    const float* __restrict__ idxF, float* __restrict__ out0){
  int b = blockIdx.x, tid = threadIdx.x;
  int id = (int)idxF[b];
  const float* xr = X + (size_t)b * DIM;
  const float* er = E + (size_t)id * DIM;
#pragma unroll
  for (int c = 0; c < 2; ++c){
    int dpos = tid + c * 256;
    float xv = xr[dpos];
    float diff = __fsub_rn(er[dpos], xv);
    out0[(size_t)b * DIM + dpos] = __fadd_rn(xv, diff);
  }
}

extern "C" void kernel_launch(void* const* d_in, const int* in_sizes, int n_in,
                              void* d_out, int out_size, void* d_ws, size_t ws_size,
                              hipStream_t stream){
  (void)in_sizes; (void)n_in;
  const float* X = (const float*)d_in[0];
  const float* E = (const float*)d_in[1];
  float* out = (float*)d_out;

  if (ws_size < 268435456ull || d_ws == nullptr){
    diagK<<<2048, 256, 0, stream>>>(out, out_size, (float)(ws_size >> 20));
    return;
  }
  float* dmat = (float*)d_ws;

  // Small scratch lives in the x_q_st region of d_out (rewritten by out0K last).
  float*  avec   = out;                              // 8192 f
  float*  hvec   = out + 8192;                       // 8192 f
  double* parts  = (double*)(out + 16384);           // 128*8192 doubles (8 MB)
  double* ak     = (double*)(out + 2113536);         // 8192 d
  double* bvec   = (double*)(out + 2129920);         // 8192 d
  double* lna    = (double*)(out + 2146304);         // 8192 d
  unsigned int* sc32 = (unsigned int*)(out + 2162688);
  float*  scf    = out + 2162690;
  double* lparts = parts;

  float* out0    = out;
  float* lossOut = out + OUT0;
  float* idxF    = out + OUT0 + 1;

  initK<<<1, 64, 0, stream>>>(sc32);
  normsK<<<64, 256, 0, stream>>>(X, E, avec, hvec);

  dim3 gg(NE / GBN, NTOK / GBM);
  gemm128<<<gg, 256, 0, stream>>>(X, E, avec, hvec, dmat, sc32);
  finalizeK<<<1, 64, 0, stream>>>(sc32, scf);

  dim3 rp(8, 128);
  rowPassK<<<rp, 256, 0, stream>>>(dmat, nullptr, scf, parts);
  reduceAK<<<32, 256, 0, stream>>>(parts, ak);
  for (int it = 0; it < 4; ++it){
    colPassK<<<NTOK, 256, 0, stream>>>(dmat, ak, scf, bvec);
    rowPassK<<<rp, 256, 0, stream>>>(dmat, bvec, scf, parts);
    reduceAK<<<32, 256, 0, stream>>>(parts, ak);
  }
  // 5th col step is a per-token positive scale -> argmax invariant -> skipped

  lnaK<<<32, 256, 0, stream>>>(ak, lna);
  argmaxLossK<<<NTOK, 256, 0, stream>>>(dmat, lna, scf, X, E, idxF, lparts);
  lossFinK<<<1, 256, 0, stream>>>(lparts, lossOut);
  out0K<<<NTOK, 256, 0, stream>>>(X, E, idxF, out0);
}

// Round 8
// 1406.433 us; speedup vs baseline: 1.0885x; 1.0885x over previous
//
#include <hip/hip_runtime.h>
#include <cfloat>
#include <cstdint>
#include <cstddef>

#define NTOK 8192
#define NE   8192
#define DIM  512
#define OUT0 4194304   // floats in x_q_st region

// ---------------- fp64 exp, branchless, |x| <= ~482*ln2 ----------------
__device__ __forceinline__ double fexp_d(double x){
  const double L2E = 1.4426950408889634074;
  const double LN2 = 0.69314718055994530942;
  double kd = rint(x * L2E);
  double r  = fma(-kd, LN2, x);                 // |r| <= 0.3466
  double p = 2.4801587301587301566e-05;         // 1/8!
  p = fma(p, r, 1.9841269841269841253e-04);     // 1/7!
  p = fma(p, r, 1.3888888888888889419e-03);     // 1/6!
  p = fma(p, r, 8.3333333333333332177e-03);     // 1/5!
  p = fma(p, r, 4.1666666666666664354e-02);     // 1/4!
  p = fma(p, r, 1.6666666666666665741e-01);     // 1/3!
  p = fma(p, r, 5.0e-01);
  p = fma(p, r, 1.0);
  p = fma(p, r, 1.0);
  long long eb = ((long long)(1023 + (int)kd)) << 52;
  return p * __longlong_as_double(eb);
}

__device__ __forceinline__ unsigned int f2ord(float f){
  unsigned int u = __float_as_uint(f);
  return (u & 0x80000000u) ? ~u : (u | 0x80000000u);
}
__device__ __forceinline__ float ord2f(unsigned int v){
  unsigned int u = (v & 0x80000000u) ? (v ^ 0x80000000u) : ~v;
  return __uint_as_float(u);
}

// ---------------- numpy pairwise sum of squares (exact order) ----------------
__device__ float pw128_sq(const float* __restrict__ p){
  float r[8];
#pragma unroll
  for (int j = 0; j < 8; ++j) r[j] = __fmul_rn(p[j], p[j]);
#pragma unroll
  for (int i = 8; i < 128; i += 8)
#pragma unroll
    for (int j = 0; j < 8; ++j) r[j] = __fadd_rn(r[j], __fmul_rn(p[i+j], p[i+j]));
  float s01 = __fadd_rn(r[0], r[1]), s23 = __fadd_rn(r[2], r[3]);
  float s45 = __fadd_rn(r[4], r[5]), s67 = __fadd_rn(r[6], r[7]);
  return __fadd_rn(__fadd_rn(s01, s23), __fadd_rn(s45, s67));
}
__device__ float pw512_sq(const float* __restrict__ p){
  float s0 = __fadd_rn(pw128_sq(p),       pw128_sq(p + 128));
  float s1 = __fadd_rn(pw128_sq(p + 256), pw128_sq(p + 384));
  return __fadd_rn(s0, s1);
}

// blocks 0..31 -> X norms, 32..63 -> E norms
__global__ __launch_bounds__(256) void normsK(const float* __restrict__ X, const float* __restrict__ E,
    float* __restrict__ avec, float* __restrict__ hvec){
  int blk = blockIdx.x;
  int i = (blk & 31) * 256 + threadIdx.x;
  if (blk < 32) avec[i] = pw512_sq(X + (size_t)i * DIM);
  else          hvec[i] = pw512_sq(E + (size_t)i * DIM);
}

__global__ void initK(unsigned int* sc32){
  if (threadIdx.x == 0){ sc32[0] = 0u; sc32[1] = 0xFFFFFFFFu; }
}

__global__ void finalizeK(const unsigned int* sc32, float* scf){
  if (threadIdx.x == 0){
    float mx = ord2f(sc32[0]);
    float mn = ord2f(sc32[1]);
    float middle = __fmul_rn(__fadd_rn(mx, mn), 0.5f);
    float amp    = __fadd_rn(__fsub_rn(mx, middle), 1e-5f);
    scf[0] = middle; scf[1] = amp;
  }
}

__global__ void diagK(float* __restrict__ out, int n, float tag){
  int i = blockIdx.x * blockDim.x + threadIdx.x;
  int stride = gridDim.x * blockDim.x;
  for (; i < n; i += stride) out[i] = (i == OUT0) ? tag : 0.f;
}

// ---------------- fp32 GEMM 128x128x16, 8x8/thread (split 4+4), k-ascending FMA ----------------
// Round-6 config (best measured: 775us, VGPR 64, no spill, conflicts 3.5%).
// BK=16 staging writes exact 2-way (free); As reads broadcast; Bs reads 2-way (free).
// launch_bounds(256,4): 128 VGPR cap fits 64 acc + operands. DO NOT raise tile (spills) or
// waves/EU (85-cap spilled 8x) — both measured regressions.
#define GBM 128
#define GBN 128
#define GBK 16
#define GLDT 132
__global__ __launch_bounds__(256, 4) void gemm128(const float* __restrict__ X, const float* __restrict__ E,
    const float* __restrict__ avec, const float* __restrict__ hvec,
    float* __restrict__ dmat, unsigned int* __restrict__ sc32){
  __shared__ float As[GBK][GLDT];
  __shared__ float Bs[GBK][GLDT];
  __shared__ float red[256];
  int tid = threadIdx.x;
  int tx = tid & 15, ty = tid >> 4;
  int bm = blockIdx.y * GBM, bn = blockIdx.x * GBN;

  float acc[2][4][2][4];
#pragma unroll
  for (int ih = 0; ih < 2; ++ih)
#pragma unroll
    for (int i = 0; i < 4; ++i)
#pragma unroll
      for (int jh = 0; jh < 2; ++jh)
#pragma unroll
        for (int j = 0; j < 4; ++j) acc[ih][i][jh][j] = 0.f;

  for (int kt = 0; kt < DIM; kt += GBK){
#pragma unroll
    for (int s = 0; s < 2; ++s){
      int flat = tid + s * 256;          // 0..511
      int m  = flat >> 2;                // 0..127
      int k4 = (flat & 3) * 4;           // 0,4,8,12
      float4 va = *(const float4*)(X + (size_t)(bm + m) * DIM + kt + k4);
      As[k4+0][m] = va.x; As[k4+1][m] = va.y; As[k4+2][m] = va.z; As[k4+3][m] = va.w;
      float4 vb = *(const float4*)(E + (size_t)(bn + m) * DIM + kt + k4);
      Bs[k4+0][m] = vb.x; Bs[k4+1][m] = vb.y; Bs[k4+2][m] = vb.z; Bs[k4+3][m] = vb.w;
    }
    __syncthreads();
#pragma unroll
    for (int kk = 0; kk < GBK; ++kk){
      float a[2][4], b[2][4];
      *(float4*)a[0] = *(const float4*)&As[kk][ty * 4];
      *(float4*)a[1] = *(const float4*)&As[kk][64 + ty * 4];
      *(float4*)b[0] = *(const float4*)&Bs[kk][tx * 4];
      *(float4*)b[1] = *(const float4*)&Bs[kk][64 + tx * 4];
#pragma unroll
      for (int ih = 0; ih < 2; ++ih)
#pragma unroll
        for (int i = 0; i < 4; ++i)
#pragma unroll
          for (int jh = 0; jh < 2; ++jh)
#pragma unroll
            for (int j = 0; j < 4; ++j)
              acc[ih][i][jh][j] = fmaf(a[ih][i], b[jh][j], acc[ih][i][jh][j]);
    }
    __syncthreads();
  }

  float lmax = -FLT_MAX, lmin = FLT_MAX;
#pragma unroll
  for (int ih = 0; ih < 2; ++ih){
#pragma unroll
    for (int i = 0; i < 4; ++i){
      int gr = bm + ih * 64 + ty * 4 + i;
      float a = avec[gr];
#pragma unroll
      for (int jh = 0; jh < 2; ++jh){
        float dv[4];
#pragma unroll
        for (int j = 0; j < 4; ++j){
          int gc = bn + jh * 64 + tx * 4 + j;
          float t = __fadd_rn(a, hvec[gc]);                  // fl(a_b + h_k)
          float d = __fsub_rn(t, 2.0f * acc[ih][i][jh][j]);  // fl(t - 2c)
          dv[j] = d;
          lmax = fmaxf(lmax, d); lmin = fminf(lmin, d);
        }
        *(float4*)(dmat + (size_t)gr * NE + bn + jh * 64 + tx * 4) = *(float4*)&dv[0];
      }
    }
  }
  red[tid] = lmax; __syncthreads();
  for (int s = 128; s > 0; s >>= 1){ if (tid < s) red[tid] = fmaxf(red[tid], red[tid+s]); __syncthreads(); }
  float bmax = red[0];
  __syncthreads();
  red[tid] = lmin; __syncthreads();
  for (int s = 128; s > 0; s >>= 1){ if (tid < s) red[tid] = fminf(red[tid], red[tid+s]); __syncthreads(); }
  if (tid == 0){
    atomicMax(&sc32[0], f2ord(bmax));
    atomicMin(&sc32[1], f2ord(red[0]));
  }
}

// ---------------- Sinkhorn sweeps over dc (dmat holds dc after rowPass<true>) ----------------
// dc stored = fl32((d-middle)/amp) — bit-identical to what every pass computed inline before,
// and to the reference's ((d-middle)/amplitude).astype(f64). EXPC reads dc directly.
#define EXPC(x) fexp_d((double)(x) * NIE)

// row step: r_k = sum_b exp(dc*NIE) * w_b ; 4 independent per-k fp64 chains per thread.
// CONVERT (pass 1 only): reads d, converts to dc in place (each element owned by one block).
template<bool CONVERT>
__global__ __launch_bounds__(256) void rowPassK(float* __restrict__ dmat, const double* __restrict__ wvec,
    const float* __restrict__ scf, double* __restrict__ partials){
  int tid = threadIdx.x;
  int k0 = (blockIdx.x * 256 + tid) * 4;
  int b0 = blockIdx.y * 64;
  const double NIE = -(1.0 / 0.003);
  float* p = dmat + (size_t)b0 * NE + k0;
  double a0 = 0.0, a1 = 0.0, a2 = 0.0, a3 = 0.0;
  if (CONVERT){
    float middle = scf[0], amp = scf[1];
    for (int bb = 0; bb < 64; ++bb){
      float4 v = *(const float4*)(p + (size_t)bb * NE);
      float c0 = __fdiv_rn(__fsub_rn(v.x, middle), amp);
      float c1 = __fdiv_rn(__fsub_rn(v.y, middle), amp);
      float c2 = __fdiv_rn(__fsub_rn(v.z, middle), amp);
      float c3 = __fdiv_rn(__fsub_rn(v.w, middle), amp);
      float4 w; w.x = c0; w.y = c1; w.z = c2; w.w = c3;
      *(float4*)(p + (size_t)bb * NE) = w;
      a0 += EXPC(c0); a1 += EXPC(c1); a2 += EXPC(c2); a3 += EXPC(c3);
    }
  } else {
    for (int bb = 0; bb < 64; bb += 2){
      float4 v0 = *(const float4*)(p + (size_t)(bb+0) * NE);
      float4 v1 = *(const float4*)(p + (size_t)(bb+1) * NE);
      double w0 = wvec[b0+bb+0], w1 = wvec[b0+bb+1];
      a0 = fma(EXPC(v0.x), w0, a0); a1 = fma(EXPC(v0.y), w0, a1);
      a2 = fma(EXPC(v0.z), w0, a2); a3 = fma(EXPC(v0.w), w0, a3);
      a0 = fma(EXPC(v1.x), w1, a0); a1 = fma(EXPC(v1.y), w1, a1);
      a2 = fma(EXPC(v1.z), w1, a2); a3 = fma(EXPC(v1.w), w1, a3);
    }
  }
  double* q = partials + (size_t)blockIdx.y * NE + k0;
  q[0] = a0; q[1] = a1; q[2] = a2; q[3] = a3;
}

__global__ void reduceAK(const double* __restrict__ partials, double* __restrict__ ak){
  int k = blockIdx.x * 256 + threadIdx.x;
  double s = 0.0;
  for (int c = 0; c < 128; ++c) s += partials[(size_t)c * NE + k];
  ak[k] = 1.0 / (8192.0 * s);
}

// col step: coalesced float4 loads, 4 independent fp64 chains (fp64 reassoc only — safe)
__global__ __launch_bounds__(256) void colPassK(const float* __restrict__ dmat, const double* __restrict__ ak,
    double* __restrict__ bvec){
  __shared__ double sd[256];
  int b = blockIdx.x, tid = threadIdx.x;
  const double NIE = -(1.0 / 0.003);
  const float* row = dmat + (size_t)b * NE;
  double c0 = 0.0, c1 = 0.0, c2 = 0.0, c3 = 0.0;
#pragma unroll 2
  for (int kb = 0; kb < 8; ++kb){
    int k = kb * 1024 + tid * 4;
    float4 v = *(const float4*)(row + k);
    double q0 = ak[k], q1 = ak[k+1], q2 = ak[k+2], q3 = ak[k+3];
    c0 = fma(EXPC(v.x), q0, c0);
    c1 = fma(EXPC(v.y), q1, c1);
    c2 = fma(EXPC(v.z), q2, c2);
    c3 = fma(EXPC(v.w), q3, c3);
  }
  sd[tid] = (c0 + c1) + (c2 + c3); __syncthreads();
  for (int s = 128; s > 0; s >>= 1){ if (tid < s) sd[tid] += sd[tid+s]; __syncthreads(); }
  if (tid == 0) bvec[b] = 1.0 / (8192.0 * sd[0]);
}

__global__ void lnaK(const double* __restrict__ ak, double* __restrict__ lna){
  int k = blockIdx.x * 256 + threadIdx.x;
  lna[k] = log(ak[k]);
}

// argmax_k [ ln a_k + dc*NIE ] fused with loss partial for the token
__global__ __launch_bounds__(256) void argmaxLossK(const float* __restrict__ dmat, const double* __restrict__ lna,
    const float* __restrict__ X, const float* __restrict__ E,
    float* __restrict__ idxF, double* __restrict__ lparts){
  __shared__ double sv[256];
  __shared__ int    si[256];
  __shared__ int    sidx;
  int b = blockIdx.x, tid = threadIdx.x;
  const double NIE = -(1.0 / 0.003);
  const float* row = dmat + (size_t)b * NE;
  double best = -1.0e300; int bk = NE;
#pragma unroll 2
  for (int c = 0; c < 8; ++c){
    int k = c * 1024 + tid * 4;
    float4 v = *(const float4*)(row + k);
    double l0 = lna[k], l1 = lna[k+1], l2 = lna[k+2], l3 = lna[k+3];
    double t0 = fma((double)v.x, NIE, l0);
    double t1 = fma((double)v.y, NIE, l1);
    double t2 = fma((double)v.z, NIE, l2);
    double t3 = fma((double)v.w, NIE, l3);
    if (t0 > best){ best = t0; bk = k; }
    if (t1 > best){ best = t1; bk = k+1; }
    if (t2 > best){ best = t2; bk = k+2; }
    if (t3 > best){ best = t3; bk = k+3; }
  }
  sv[tid] = best; si[tid] = bk; __syncthreads();
  for (int s = 128; s > 0; s >>= 1){
    if (tid < s){
      double o = sv[tid+s]; int ok = si[tid+s];
      if (o > sv[tid] || (o == sv[tid] && ok < si[tid])){ sv[tid] = o; si[tid] = ok; }
    }
    __syncthreads();
  }
  if (tid == 0){ idxF[b] = (float)si[0]; sidx = si[0]; }
  __syncthreads();

  // fused loss partial
  int id = sidx;
  const float* xr = X + (size_t)b * DIM;
  const float* er = E + (size_t)id * DIM;
  double ls = 0.0;
#pragma unroll
  for (int c = 0; c < 2; ++c){
    int dpos = tid + c * 256;
    float diff = __fsub_rn(er[dpos], xr[dpos]);
    ls = fma((double)diff, (double)diff, ls);
  }
  sv[tid] = ls; __syncthreads();
  for (int s = 128; s > 0; s >>= 1){ if (tid < s) sv[tid] += sv[tid+s]; __syncthreads(); }
  if (tid == 0) lparts[b] = sv[0];
}

__global__ __launch_bounds__(256) void lossFinK(const double* __restrict__ lparts, float* __restrict__ lossOut){
  __shared__ double sd[256];
  int tid = threadIdx.x;
  double s = 0.0;
  for (int b = tid; b < NTOK; b += 256) s += lparts[b];
  sd[tid] = s; __syncthreads();
  for (int st = 128; st > 0; st >>= 1){ if (tid < st) sd[tid] += sd[tid+st]; __syncthreads(); }
  if (tid == 0){
    double v = sd[0] / (double)((size_t)NTOK * DIM);
    float vf = (float)v;
    lossOut[0] = __fadd_rn(vf, __fmul_rn(0.25f, vf));
  }
}

__global__ __launch_bounds__(256) void out0K(const float* __restrict__ X, const float* __restrict__ E,
    const float* __restrict__ idxF, float* __restrict__ out0){
  int b = blockIdx.x, tid = threadIdx.x;
  int id = (int)idxF[b];
  const float* xr = X + (size_t)b * DIM;
  const float* er = E + (size_t)id * DIM;
#pragma unroll
  for (int c = 0; c < 2; ++c){
    int dpos = tid + c * 256;
    float xv = xr[dpos];
    float diff = __fsub_rn(er[dpos], xv);
    out0[(size_t)b * DIM + dpos] = __fadd_rn(xv, diff);
  }
}

extern "C" void kernel_launch(void* const* d_in, const int* in_sizes, int n_in,
                              void* d_out, int out_size, void* d_ws, size_t ws_size,
                              hipStream_t stream){
  (void)in_sizes; (void)n_in;
  const float* X = (const float*)d_in[0];
  const float* E = (const float*)d_in[1];
  float* out = (float*)d_out;

  if (ws_size < 268435456ull || d_ws == nullptr){
    diagK<<<2048, 256, 0, stream>>>(out, out_size, (float)(ws_size >> 20));
    return;
  }
  float* dmat = (float*)d_ws;

  // Small scratch lives in the x_q_st region of d_out (rewritten by out0K last).
  float*  avec   = out;                              // 8192 f
  float*  hvec   = out + 8192;                       // 8192 f
  double* parts  = (double*)(out + 16384);           // 128*8192 doubles (8 MB)
  double* ak     = (double*)(out + 2113536);         // 8192 d
  double* bvec   = (double*)(out + 2129920);         // 8192 d
  double* lna    = (double*)(out + 2146304);         // 8192 d
  unsigned int* sc32 = (unsigned int*)(out + 2162688);
  float*  scf    = out + 2162690;
  double* lparts = parts;

  float* out0    = out;
  float* lossOut = out + OUT0;
  float* idxF    = out + OUT0 + 1;

  initK<<<1, 64, 0, stream>>>(sc32);
  normsK<<<64, 256, 0, stream>>>(X, E, avec, hvec);

  dim3 gg(NE / GBN, NTOK / GBM);
  gemm128<<<gg, 256, 0, stream>>>(X, E, avec, hvec, dmat, sc32);
  finalizeK<<<1, 64, 0, stream>>>(sc32, scf);

  dim3 rp(8, 128);
  rowPassK<true><<<rp, 256, 0, stream>>>(dmat, nullptr, scf, parts);   // converts d -> dc in place
  reduceAK<<<32, 256, 0, stream>>>(parts, ak);
  for (int it = 0; it < 4; ++it){
    colPassK<<<NTOK, 256, 0, stream>>>(dmat, ak, bvec);
    rowPassK<false><<<rp, 256, 0, stream>>>(dmat, bvec, scf, parts);
    reduceAK<<<32, 256, 0, stream>>>(parts, ak);
  }
  // 5th col step is a per-token positive scale -> argmax invariant -> skipped

  lnaK<<<32, 256, 0, stream>>>(ak, lna);
  argmaxLossK<<<NTOK, 256, 0, stream>>>(dmat, lna, X, E, idxF, lparts);
  lossFinK<<<1, 256, 0, stream>>>(lparts, lossOut);
  out0K<<<NTOK, 256, 0, stream>>>(X, E, idxF, out0);
}